// Round 5
// baseline (594.559 us; speedup 1.0000x reference)
//
#include <hip/hip_runtime.h>

typedef unsigned short u16;
typedef __attribute__((ext_vector_type(8))) short short8;
typedef __attribute__((ext_vector_type(4))) float floatx4;

#define MFMA16(a, b, c) __builtin_amdgcn_mfma_f32_16x16x32_bf16(a, b, c, 0, 0, 0)

__device__ __forceinline__ float bf2f(u16 u) {
  return __uint_as_float(((unsigned int)u) << 16);
}
__device__ __forceinline__ u16 f2bf(float f) {
  unsigned int u = __float_as_uint(f);
  unsigned int r = (u + 0x7fffu + ((u >> 16) & 1u)) >> 16;
  return (u16)r;
}
// async global->LDS, 16B/lane; LDS dest = wave-uniform base + lane*16 (HW rule)
__device__ __forceinline__ void gl_lds16(const u16* g, u16* lds_wave_base) {
  __builtin_amdgcn_global_load_lds(
      (const __attribute__((address_space(1))) unsigned int*)g,
      (__attribute__((address_space(3))) unsigned int*)lds_wave_base, 16, 0, 0);
}

// ---------------------------------------------------------------- LayerNorm: fp32 x -> bf16 h
__global__ __launch_bounds__(256) void ln_kernel(
    const float* __restrict__ x, const float* __restrict__ w, const float* __restrict__ bb,
    u16* __restrict__ hb)
{
  int wid = threadIdx.x >> 6, lane = threadIdx.x & 63;
  int row = blockIdx.x * 4 + wid;
  const float* xr = x + row * 1024 + lane * 16;
  float xs[16];
#pragma unroll
  for (int i = 0; i < 4; i++) {
    float4 v = *(const float4*)(xr + i * 4);
    xs[i * 4 + 0] = v.x; xs[i * 4 + 1] = v.y; xs[i * 4 + 2] = v.z; xs[i * 4 + 3] = v.w;
  }
  float s = 0.f, ss = 0.f;
#pragma unroll
  for (int i = 0; i < 16; i++) { s += xs[i]; ss += xs[i] * xs[i]; }
#pragma unroll
  for (int m = 1; m < 64; m <<= 1) { s += __shfl_xor(s, m, 64); ss += __shfl_xor(ss, m, 64); }
  float mu = s * (1.0f / 1024.0f);
  float var = ss * (1.0f / 1024.0f) - mu * mu;
  float rstd = rsqrtf(var + 1e-5f);
  const float* wr = w + lane * 16;
  const float* br = bb + lane * 16;
  short8 o0, o1;
#pragma unroll
  for (int i = 0; i < 8; i++) {
    o0[i] = (short)f2bf((xs[i] - mu) * rstd * wr[i] + br[i]);
    o1[i] = (short)f2bf((xs[8 + i] - mu) * rstd * wr[8 + i] + br[8 + i]);
  }
  u16* hr = hb + row * 1024 + lane * 16;
  *(short8*)hr = o0;
  *(short8*)(hr + 8) = o1;
}

// ---------------------------------------------------------------- convert wq|wk|wv|wo fp32 -> bf16
__global__ __launch_bounds__(256) void convw_kernel(
    const float* __restrict__ wq, const float* __restrict__ wk,
    const float* __restrict__ wv, const float* __restrict__ wo,
    u16* __restrict__ wb)
{
  int idx = (blockIdx.x * 256 + threadIdx.x) * 8;  // [0, 4M)
  int seg = idx >> 20, off = idx & 1048575;
  const float* s = (seg == 0) ? wq : (seg == 1) ? wk : (seg == 2) ? wv : wo;
  float4 f0 = *(const float4*)(s + off);
  float4 f1 = *(const float4*)(s + off + 4);
  short8 o;
  o[0] = (short)f2bf(f0.x); o[1] = (short)f2bf(f0.y);
  o[2] = (short)f2bf(f0.z); o[3] = (short)f2bf(f0.w);
  o[4] = (short)f2bf(f1.x); o[5] = (short)f2bf(f1.y);
  o[6] = (short)f2bf(f1.z); o[7] = (short)f2bf(f1.w);
  *(short8*)&wb[idx] = o;
}

// ---------------------------------------------------------------- fused QKV GEMM (bf16)
// async global_load_lds staging: LDS byte offset of thread = tid*16, so per-wave
// dest = base + wid*1024B + lane*16B  -> satisfies wave-uniform-base rule.
__global__ __launch_bounds__(256) void qkv_kernel(
    const u16* __restrict__ hb, const u16* __restrict__ wb,
    const float* __restrict__ bq, const float* __restrict__ bk, const float* __restrict__ bv,
    u16* __restrict__ qs, u16* __restrict__ kko, u16* __restrict__ vt)
{
  __shared__ u16 As[128 * 32];
  __shared__ u16 Bs[128 * 32];
  int tid = threadIdx.x;
  int wid = tid >> 6, lane = tid & 63;
  int wm = wid >> 1, wn = wid & 1;
  int l15 = lane & 15, quad = lane >> 4;
  int m0 = blockIdx.y * 128;
  int n0g = blockIdx.x * 128;
  int sec = n0g >> 10;
  int n0 = n0g & 1023;
  const u16* W = wb + sec * 1048576;
  const float* bias = (sec == 0) ? bq : ((sec == 1) ? bk : bv);

  floatx4 zero4 = {0.f, 0.f, 0.f, 0.f};
  floatx4 acc[4][4];
#pragma unroll
  for (int i = 0; i < 4; i++)
#pragma unroll
    for (int j = 0; j < 4; j++) acc[i][j] = zero4;

  int lr = tid >> 2;
  int lc = (tid & 3) * 8;
  u16* asw = As + wid * 512;   // wid*1024 bytes
  u16* bsw = Bs + wid * 512;

  for (int kt = 0; kt < 1024; kt += 32) {
    gl_lds16(&hb[(m0 + lr) * 1024 + kt + lc],      asw);
    gl_lds16(&hb[(m0 + lr + 64) * 1024 + kt + lc], asw + 2048);
    gl_lds16(&W[(n0 + lr) * 1024 + kt + lc],       bsw);
    gl_lds16(&W[(n0 + lr + 64) * 1024 + kt + lc],  bsw + 2048);
    __syncthreads();
    short8 af[4], bf[4];
#pragma unroll
    for (int mi = 0; mi < 4; mi++)
      af[mi] = *(const short8*)&As[(wm * 64 + mi * 16 + l15) * 32 + quad * 8];
#pragma unroll
    for (int ni = 0; ni < 4; ni++)
      bf[ni] = *(const short8*)&Bs[(wn * 64 + ni * 16 + l15) * 32 + quad * 8];
#pragma unroll
    for (int mi = 0; mi < 4; mi++)
#pragma unroll
      for (int ni = 0; ni < 4; ni++)
        acc[mi][ni] = MFMA16(af[mi], bf[ni], acc[mi][ni]);
    __syncthreads();
  }

  int bidx = m0 >> 10;
#pragma unroll
  for (int mi = 0; mi < 4; mi++) {
#pragma unroll
    for (int ni = 0; ni < 4; ni++) {
#pragma unroll
      for (int r = 0; r < 4; r++) {
        int row = m0 + wm * 64 + mi * 16 + quad * 4 + r;
        int t = row & 1023;
        int c = n0 + wn * 64 + ni * 16 + l15;
        float val = acc[mi][ni][r] + bias[c];
        int hh = c >> 6, hp = c & 63;
        if (sec == 0) {
          val *= 0.125f;
          qs[((bidx * 16 + hh) * 1024 + t) * 64 + hp] = f2bf(val);
        } else if (sec == 1) {
          kko[((bidx * 16 + hh) * 1024 + t) * 64 + hp] = f2bf(val);
        } else {
          vt[((bidx * 16 + hh) * 64 + hp) * 1024 + t] = f2bf(val);
        }
      }
    }
  }
}

// ---------------------------------------------------------------- relative bucket + pos_bias
__device__ __forceinline__ int rel_bucket(int t, int s) {
  int rel = s - t;
  int bucket = (rel > 0) ? 160 : 0;
  int n = (rel < 0) ? -rel : rel;
  if (n < 80) return bucket + n;
  float a = logf((float)n / 80.0f);
  float c = a / (float)2.302585092994046;   // np.log(10.0)
  float v = c * 80.0f;
  int large = 80 + (int)v;
  if (large > 159) large = 159;
  return bucket + large;
}

// writes fp32 b=0 slice (+ b=1..3 if nb4) AND a bf16 [h][t][s] copy for attn
__global__ __launch_bounds__(256) void bias0_kernel(
    const float* __restrict__ rel_emb, float* __restrict__ out1,
    u16* __restrict__ bh16, int nb4)
{
  int tid = blockIdx.x * 256 + threadIdx.x;  // 131072 total
  int t = tid >> 7;
  int s0 = (tid & 127) * 8;
  int bkt[8];
#pragma unroll
  for (int j = 0; j < 8; j++) bkt[j] = rel_bucket(t, s0 + j) * 16;
  int base_ts = t * 1024 + s0;
#pragma unroll
  for (int hh = 0; hh < 16; hh++) {
    float4 v0, v1;
    v0.x = rel_emb[bkt[0] + hh]; v0.y = rel_emb[bkt[1] + hh];
    v0.z = rel_emb[bkt[2] + hh]; v0.w = rel_emb[bkt[3] + hh];
    v1.x = rel_emb[bkt[4] + hh]; v1.y = rel_emb[bkt[5] + hh];
    v1.z = rel_emb[bkt[6] + hh]; v1.w = rel_emb[bkt[7] + hh];
    float* p = out1 + hh * 1048576 + base_ts;
    *(float4*)p = v0;
    *(float4*)(p + 4) = v1;
    if (nb4) {
      *(float4*)(p + 16777216) = v0; *(float4*)(p + 16777216 + 4) = v1;
      *(float4*)(p + 33554432) = v0; *(float4*)(p + 33554432 + 4) = v1;
      *(float4*)(p + 50331648) = v0; *(float4*)(p + 50331648 + 4) = v1;
    }
    short8 o;
    o[0] = (short)f2bf(v0.x); o[1] = (short)f2bf(v0.y);
    o[2] = (short)f2bf(v0.z); o[3] = (short)f2bf(v0.w);
    o[4] = (short)f2bf(v1.x); o[5] = (short)f2bf(v1.y);
    o[6] = (short)f2bf(v1.z); o[7] = (short)f2bf(v1.w);
    *(short8*)(bh16 + hh * 1048576 + base_ts) = o;
  }
}

// ---------------------------------------------------------------- replicate b=0 -> b=1,2,3 (fallback path only)
__global__ __launch_bounds__(256) void bias_copy_kernel(float* __restrict__ out1)
{
  int idx = blockIdx.x * 256 + threadIdx.x;  // [0, 4M) units of float4
  float4 v = *(const float4*)&out1[idx * 4];
  *(float4*)&out1[16777216 + idx * 4] = v;
  *(float4*)&out1[33554432 + idx * 4] = v;
  *(float4*)&out1[50331648 + idx * 4] = v;
}

// ---------------------------------------------------------------- flash attention (gate fused, s-step 64)
// grid (64 bh, 16 qtiles); 4 waves/block, each wave owns 16 q-rows.
__global__ __launch_bounds__(256) void attn_kernel(
    const u16* __restrict__ qs, const u16* __restrict__ kko, const u16* __restrict__ vt,
    const float* __restrict__ gw, const float* __restrict__ gb, const float* __restrict__ ga,
    const u16* __restrict__ bh16, u16* __restrict__ ao)
{
  __shared__ __align__(16) u16 Pb[4][16 * 64];
  int wid = threadIdx.x >> 6, lane = threadIdx.x & 63;
  int l15 = lane & 15, quad = lane >> 4;
  int bh = blockIdx.x;
  int b = bh >> 4, h = bh & 15;
  int q0 = blockIdx.y * 64 + wid * 16;
  const u16* Q = qs + bh * 65536;
  const u16* K = kko + bh * 65536;
  const u16* V = vt + bh * 65536;        // [hd][t]
  const u16* Bi = bh16 + h * 1048576;    // bf16 [t][s]
  u16* pb = &Pb[wid][0];

  // ---- gate for row q0 + l15 (all lanes compute; quads duplicate) ----
  const u16* qrow = Q + (q0 + l15) * 64;
  float e[8];
#pragma unroll
  for (int i = 0; i < 8; i++) e[i] = gb[i];
  for (int j = 0; j < 64; j++) {
    float ql = bf2f(qrow[j]) * 256.0f;   // qs holds q*0.125; ql = raw_q*32
#pragma unroll
    for (int i = 0; i < 8; i++) e[i] += ql * gw[i * 64 + j];
  }
  float u0 = e[0] + e[1] + e[2] + e[3];
  float u1 = e[4] + e[5] + e[6] + e[7];
  float sa = 1.0f / (1.0f + __expf(-u0));
  float sb = 1.0f / (1.0f + __expf(-u1));
  float gv = sa * (sb * ga[h] - 1.0f) + 2.0f;

  short8 qf0 = *(const short8*)&Q[(q0 + l15) * 64 + quad * 8];
  short8 qf1 = *(const short8*)&Q[(q0 + l15) * 64 + quad * 8 + 32];
  float gt[4], mrun[4], lrun[4];
#pragma unroll
  for (int r = 0; r < 4; r++) {
    gt[r] = __shfl(gv, quad * 4 + r, 64);
    mrun[r] = -1e30f;
    lrun[r] = 0.f;
  }
  floatx4 zero4 = {0.f, 0.f, 0.f, 0.f};
  floatx4 accO[4];
#pragma unroll
  for (int ni = 0; ni < 4; ni++) accO[ni] = zero4;

  for (int s0 = 0; s0 < 1024; s0 += 64) {
    floatx4 sc[4];
#pragma unroll
    for (int j = 0; j < 4; j++) sc[j] = zero4;
    short8 kf;
#pragma unroll
    for (int j = 0; j < 4; j++) {
      kf = *(const short8*)&K[(s0 + j * 16 + l15) * 64 + quad * 8];
      sc[j] = MFMA16(qf0, kf, sc[j]);
      kf = *(const short8*)&K[(s0 + j * 16 + l15) * 64 + quad * 8 + 32];
      sc[j] = MFMA16(qf1, kf, sc[j]);
    }

#pragma unroll
    for (int r = 0; r < 4; r++) {
      int t = q0 + quad * 4 + r;
      float v[4];
#pragma unroll
      for (int j = 0; j < 4; j++)
        v[j] = sc[j][r] + gt[r] * bf2f(Bi[t * 1024 + s0 + j * 16 + l15]);
      float mt = fmaxf(fmaxf(v[0], v[1]), fmaxf(v[2], v[3]));
#pragma unroll
      for (int m = 1; m < 16; m <<= 1) mt = fmaxf(mt, __shfl_xor(mt, m, 64));
      float mnew = fmaxf(mrun[r], mt);
      float alpha = __expf(fmaxf(mrun[r] - mnew, -80.0f));  // first-iter safe
      float p[4], ps = 0.f;
#pragma unroll
      for (int j = 0; j < 4; j++) { p[j] = __expf(v[j] - mnew); ps += p[j]; }
#pragma unroll
      for (int m = 1; m < 16; m <<= 1) ps += __shfl_xor(ps, m, 64);
      lrun[r] = lrun[r] * alpha + ps;
      mrun[r] = mnew;
#pragma unroll
      for (int ni = 0; ni < 4; ni++) accO[ni][r] *= alpha;
#pragma unroll
      for (int j = 0; j < 4; j++)
        pb[(quad * 4 + r) * 64 + j * 16 + l15] = f2bf(p[j]);
    }
    __syncthreads();   // uniform trip count; orders Pb write -> cross-lane read
    short8 pf0 = *(const short8*)&pb[l15 * 64 + quad * 8];
    short8 pf1 = *(const short8*)&pb[l15 * 64 + 32 + quad * 8];
#pragma unroll
    for (int ni = 0; ni < 4; ni++) {
      short8 vf = *(const short8*)&V[(ni * 16 + l15) * 1024 + s0 + quad * 8];
      accO[ni] = MFMA16(pf0, vf, accO[ni]);
      vf = *(const short8*)&V[(ni * 16 + l15) * 1024 + s0 + 32 + quad * 8];
      accO[ni] = MFMA16(pf1, vf, accO[ni]);
    }
  }
#pragma unroll
  for (int ni = 0; ni < 4; ni++) {
#pragma unroll
    for (int r = 0; r < 4; r++) {
      int t = q0 + quad * 4 + r;
      float val = accO[ni][r] / lrun[r];
      ao[(b * 1024 + t) * 1024 + h * 64 + ni * 16 + l15] = f2bf(val);
    }
  }
}

// ---------------------------------------------------------------- output projection + residual (fp32 out)
__global__ __launch_bounds__(256) void oproj_kernel(
    const u16* __restrict__ ao, const u16* __restrict__ wob, const float* __restrict__ bo,
    const float* __restrict__ x, float* __restrict__ out)
{
  __shared__ u16 As[128 * 32];
  __shared__ u16 Bs[128 * 32];
  int tid = threadIdx.x;
  int wid = tid >> 6, lane = tid & 63;
  int wm = wid >> 1, wn = wid & 1;
  int l15 = lane & 15, quad = lane >> 4;
  int m0 = blockIdx.y * 128;
  int n0 = blockIdx.x * 128;

  floatx4 zero4 = {0.f, 0.f, 0.f, 0.f};
  floatx4 acc[4][4];
#pragma unroll
  for (int i = 0; i < 4; i++)
#pragma unroll
    for (int j = 0; j < 4; j++) acc[i][j] = zero4;

  int lr = tid >> 2;
  int lc = (tid & 3) * 8;
  u16* asw = As + wid * 512;
  u16* bsw = Bs + wid * 512;

  for (int kt = 0; kt < 1024; kt += 32) {
    gl_lds16(&ao[(m0 + lr) * 1024 + kt + lc],       asw);
    gl_lds16(&ao[(m0 + lr + 64) * 1024 + kt + lc],  asw + 2048);
    gl_lds16(&wob[(n0 + lr) * 1024 + kt + lc],      bsw);
    gl_lds16(&wob[(n0 + lr + 64) * 1024 + kt + lc], bsw + 2048);
    __syncthreads();
    short8 af[4], bf[4];
#pragma unroll
    for (int mi = 0; mi < 4; mi++)
      af[mi] = *(const short8*)&As[(wm * 64 + mi * 16 + l15) * 32 + quad * 8];
#pragma unroll
    for (int ni = 0; ni < 4; ni++)
      bf[ni] = *(const short8*)&Bs[(wn * 64 + ni * 16 + l15) * 32 + quad * 8];
#pragma unroll
    for (int mi = 0; mi < 4; mi++)
#pragma unroll
      for (int ni = 0; ni < 4; ni++)
        acc[mi][ni] = MFMA16(af[mi], bf[ni], acc[mi][ni]);
    __syncthreads();
  }

#pragma unroll
  for (int mi = 0; mi < 4; mi++) {
#pragma unroll
    for (int ni = 0; ni < 4; ni++) {
#pragma unroll
      for (int r = 0; r < 4; r++) {
        int row = m0 + wm * 64 + mi * 16 + quad * 4 + r;
        int c = n0 + wn * 64 + ni * 16 + l15;
        out[row * 1024 + c] = acc[mi][ni][r] + bo[c] + x[row * 1024 + c];
      }
    }
  }
}

// ---------------------------------------------------------------- launch
extern "C" void kernel_launch(void* const* d_in, const int* in_sizes, int n_in,
                              void* d_out, int out_size, void* d_ws, size_t ws_size,
                              hipStream_t stream) {
  const float* x    = (const float*)d_in[0];
  const float* ln_w = (const float*)d_in[1];
  const float* ln_b = (const float*)d_in[2];
  const float* wq   = (const float*)d_in[3];
  const float* bq   = (const float*)d_in[4];
  const float* wk   = (const float*)d_in[5];
  const float* bk   = (const float*)d_in[6];
  const float* wv   = (const float*)d_in[7];
  const float* bv   = (const float*)d_in[8];
  const float* wo   = (const float*)d_in[9];
  const float* bo   = (const float*)d_in[10];
  const float* rel  = (const float*)d_in[11];
  const float* gw   = (const float*)d_in[12];
  const float* gb   = (const float*)d_in[13];
  const float* ga   = (const float*)d_in[14];

  float* out0  = (float*)d_out;
  float* out1f = out0 + 4194304;   // pos_bias_out, 64M floats (256 MB)

  // scratch: 80 MB total (6x8MB bf16 bufs + 32MB bf16 bias copy)
  int big_ws = (ws_size >= (size_t)(96u << 20)) ? 1 : 0;
  char* sb = big_ws ? (char*)d_ws : (char*)(out1f + 16777216);  // fallback: out1 b=1,2 regions
  u16* hbb = (u16*)(sb);                  // 8 MB  LN(x) bf16
  u16* wbb = (u16*)(sb + (8u << 20));     // 8 MB  wq|wk|wv|wo bf16
  u16* qsb = (u16*)(sb + (16u << 20));    // 8 MB  q*0.125 [b,h,t,hd]
  u16* kkb = (u16*)(sb + (24u << 20));    // 8 MB  [b,h,t,hd]
  u16* vtb = (u16*)(sb + (32u << 20));    // 8 MB  [b,h,hd,t]
  u16* aob = (u16*)(sb + (40u << 20));    // 8 MB  attn out
  u16* bhb = (u16*)(sb + (48u << 20));    // 32 MB bf16 bias [h][t][s]

  ln_kernel<<<1024, 256, 0, stream>>>(x, ln_w, ln_b, hbb);
  convw_kernel<<<2048, 256, 0, stream>>>(wq, wk, wv, wo, wbb);
  qkv_kernel<<<dim3(24, 32), 256, 0, stream>>>(hbb, wbb, bq, bk, bv, qsb, kkb, vtb);
  bias0_kernel<<<512, 256, 0, stream>>>(rel, out1f, bhb, big_ws);
  attn_kernel<<<dim3(64, 16), 256, 0, stream>>>(qsb, kkb, vtb, gw, gb, ga, bhb, aob);
  oproj_kernel<<<dim3(8, 32), 256, 0, stream>>>(aob, wbb + 3145728, bo, x, out0);
  if (!big_ws)
    bias_copy_kernel<<<16384, 256, 0, stream>>>(out1f);  // replicate b=0 -> b=1,2,3
}

// Round 6
// 552.219 us; speedup vs baseline: 1.0767x; 1.0767x over previous
//
#include <hip/hip_runtime.h>

typedef unsigned short u16;
typedef __attribute__((ext_vector_type(8))) short short8;
typedef __attribute__((ext_vector_type(4))) short short4v;
typedef __attribute__((ext_vector_type(4))) float floatx4;

#define MFMA16(a, b, c) __builtin_amdgcn_mfma_f32_16x16x32_bf16(a, b, c, 0, 0, 0)

__device__ __forceinline__ float bf2f(u16 u) {
  return __uint_as_float(((unsigned int)u) << 16);
}
__device__ __forceinline__ u16 f2bf(float f) {
  unsigned int u = __float_as_uint(f);
  unsigned int r = (u + 0x7fffu + ((u >> 16) & 1u)) >> 16;
  return (u16)r;
}
// async global->LDS, 16B/lane; LDS dest = wave-uniform base + lane*16 (HW rule)
__device__ __forceinline__ void gl_lds16(const u16* g, u16* lds_wave_base) {
  __builtin_amdgcn_global_load_lds(
      (const __attribute__((address_space(1))) unsigned int*)g,
      (__attribute__((address_space(3))) unsigned int*)lds_wave_base, 16, 0, 0);
}

// ---------------------------------------------------------------- LayerNorm: fp32 x -> bf16 h
__global__ __launch_bounds__(256) void ln_kernel(
    const float* __restrict__ x, const float* __restrict__ w, const float* __restrict__ bb,
    u16* __restrict__ hb)
{
  int wid = threadIdx.x >> 6, lane = threadIdx.x & 63;
  int row = blockIdx.x * 4 + wid;
  const float* xr = x + row * 1024 + lane * 16;
  float xs[16];
#pragma unroll
  for (int i = 0; i < 4; i++) {
    float4 v = *(const float4*)(xr + i * 4);
    xs[i * 4 + 0] = v.x; xs[i * 4 + 1] = v.y; xs[i * 4 + 2] = v.z; xs[i * 4 + 3] = v.w;
  }
  float s = 0.f, ss = 0.f;
#pragma unroll
  for (int i = 0; i < 16; i++) { s += xs[i]; ss += xs[i] * xs[i]; }
#pragma unroll
  for (int m = 1; m < 64; m <<= 1) { s += __shfl_xor(s, m, 64); ss += __shfl_xor(ss, m, 64); }
  float mu = s * (1.0f / 1024.0f);
  float var = ss * (1.0f / 1024.0f) - mu * mu;
  float rstd = rsqrtf(var + 1e-5f);
  const float* wr = w + lane * 16;
  const float* br = bb + lane * 16;
  short8 o0, o1;
#pragma unroll
  for (int i = 0; i < 8; i++) {
    o0[i] = (short)f2bf((xs[i] - mu) * rstd * wr[i] + br[i]);
    o1[i] = (short)f2bf((xs[8 + i] - mu) * rstd * wr[8 + i] + br[8 + i]);
  }
  u16* hr = hb + row * 1024 + lane * 16;
  *(short8*)hr = o0;
  *(short8*)(hr + 8) = o1;
}

// ---------------------------------------------------------------- convert wq|wk|wv|wo fp32 -> bf16
__global__ __launch_bounds__(256) void convw_kernel(
    const float* __restrict__ wq, const float* __restrict__ wk,
    const float* __restrict__ wv, const float* __restrict__ wo,
    u16* __restrict__ wb)
{
  int idx = (blockIdx.x * 256 + threadIdx.x) * 8;  // [0, 4M)
  int seg = idx >> 20, off = idx & 1048575;
  const float* s = (seg == 0) ? wq : (seg == 1) ? wk : (seg == 2) ? wv : wo;
  float4 f0 = *(const float4*)(s + off);
  float4 f1 = *(const float4*)(s + off + 4);
  short8 o;
  o[0] = (short)f2bf(f0.x); o[1] = (short)f2bf(f0.y);
  o[2] = (short)f2bf(f0.z); o[3] = (short)f2bf(f0.w);
  o[4] = (short)f2bf(f1.x); o[5] = (short)f2bf(f1.y);
  o[6] = (short)f2bf(f1.z); o[7] = (short)f2bf(f1.w);
  *(short8*)&wb[idx] = o;
}

// ---------------------------------------------------------------- fused QKV GEMM (bf16)
__global__ __launch_bounds__(256) void qkv_kernel(
    const u16* __restrict__ hb, const u16* __restrict__ wb,
    const float* __restrict__ bq, const float* __restrict__ bk, const float* __restrict__ bv,
    u16* __restrict__ qs, u16* __restrict__ kko, u16* __restrict__ vt)
{
  __shared__ u16 As[128 * 32];
  __shared__ u16 Bs[128 * 32];
  int tid = threadIdx.x;
  int wid = tid >> 6, lane = tid & 63;
  int wm = wid >> 1, wn = wid & 1;
  int l15 = lane & 15, quad = lane >> 4;
  int m0 = blockIdx.y * 128;
  int n0g = blockIdx.x * 128;
  int sec = n0g >> 10;
  int n0 = n0g & 1023;
  const u16* W = wb + sec * 1048576;
  const float* bias = (sec == 0) ? bq : ((sec == 1) ? bk : bv);

  floatx4 zero4 = {0.f, 0.f, 0.f, 0.f};
  floatx4 acc[4][4];
#pragma unroll
  for (int i = 0; i < 4; i++)
#pragma unroll
    for (int j = 0; j < 4; j++) acc[i][j] = zero4;

  int lr = tid >> 2;
  int lc = (tid & 3) * 8;
  u16* asw = As + wid * 512;   // wid*1024 bytes
  u16* bsw = Bs + wid * 512;

  for (int kt = 0; kt < 1024; kt += 32) {
    gl_lds16(&hb[(m0 + lr) * 1024 + kt + lc],      asw);
    gl_lds16(&hb[(m0 + lr + 64) * 1024 + kt + lc], asw + 2048);
    gl_lds16(&W[(n0 + lr) * 1024 + kt + lc],       bsw);
    gl_lds16(&W[(n0 + lr + 64) * 1024 + kt + lc],  bsw + 2048);
    __syncthreads();
    short8 af[4], bf[4];
#pragma unroll
    for (int mi = 0; mi < 4; mi++)
      af[mi] = *(const short8*)&As[(wm * 64 + mi * 16 + l15) * 32 + quad * 8];
#pragma unroll
    for (int ni = 0; ni < 4; ni++)
      bf[ni] = *(const short8*)&Bs[(wn * 64 + ni * 16 + l15) * 32 + quad * 8];
#pragma unroll
    for (int mi = 0; mi < 4; mi++)
#pragma unroll
      for (int ni = 0; ni < 4; ni++)
        acc[mi][ni] = MFMA16(af[mi], bf[ni], acc[mi][ni]);
    __syncthreads();
  }

  int bidx = m0 >> 10;
#pragma unroll
  for (int mi = 0; mi < 4; mi++) {
#pragma unroll
    for (int ni = 0; ni < 4; ni++) {
#pragma unroll
      for (int r = 0; r < 4; r++) {
        int row = m0 + wm * 64 + mi * 16 + quad * 4 + r;
        int t = row & 1023;
        int c = n0 + wn * 64 + ni * 16 + l15;
        float val = acc[mi][ni][r] + bias[c];
        int hh = c >> 6, hp = c & 63;
        if (sec == 0) {
          val *= 0.125f;
          qs[((bidx * 16 + hh) * 1024 + t) * 64 + hp] = f2bf(val);
        } else if (sec == 1) {
          kko[((bidx * 16 + hh) * 1024 + t) * 64 + hp] = f2bf(val);
        } else {
          vt[((bidx * 16 + hh) * 64 + hp) * 1024 + t] = f2bf(val);
        }
      }
    }
  }
}

// ---------------------------------------------------------------- relative bucket + pos_bias
__device__ __forceinline__ int rel_bucket(int t, int s) {
  int rel = s - t;
  int bucket = (rel > 0) ? 160 : 0;
  int n = (rel < 0) ? -rel : rel;
  if (n < 80) return bucket + n;
  float a = logf((float)n / 80.0f);
  float c = a / (float)2.302585092994046;   // np.log(10.0)
  float v = c * 80.0f;
  int large = 80 + (int)v;
  if (large > 159) large = 159;
  return bucket + large;
}

// writes fp32 b=0 slice (+ b=1..3 if nb4) AND a bf16 [h][t][s] copy for attn
__global__ __launch_bounds__(256) void bias0_kernel(
    const float* __restrict__ rel_emb, float* __restrict__ out1,
    u16* __restrict__ bh16, int nb4)
{
  int tid = blockIdx.x * 256 + threadIdx.x;  // 131072 total
  int t = tid >> 7;
  int s0 = (tid & 127) * 8;
  int bkt[8];
#pragma unroll
  for (int j = 0; j < 8; j++) bkt[j] = rel_bucket(t, s0 + j) * 16;
  int base_ts = t * 1024 + s0;
#pragma unroll
  for (int hh = 0; hh < 16; hh++) {
    float4 v0, v1;
    v0.x = rel_emb[bkt[0] + hh]; v0.y = rel_emb[bkt[1] + hh];
    v0.z = rel_emb[bkt[2] + hh]; v0.w = rel_emb[bkt[3] + hh];
    v1.x = rel_emb[bkt[4] + hh]; v1.y = rel_emb[bkt[5] + hh];
    v1.z = rel_emb[bkt[6] + hh]; v1.w = rel_emb[bkt[7] + hh];
    float* p = out1 + hh * 1048576 + base_ts;
    *(float4*)p = v0;
    *(float4*)(p + 4) = v1;
    if (nb4) {
      *(float4*)(p + 16777216) = v0; *(float4*)(p + 16777216 + 4) = v1;
      *(float4*)(p + 33554432) = v0; *(float4*)(p + 33554432 + 4) = v1;
      *(float4*)(p + 50331648) = v0; *(float4*)(p + 50331648 + 4) = v1;
    }
    short8 o;
    o[0] = (short)f2bf(v0.x); o[1] = (short)f2bf(v0.y);
    o[2] = (short)f2bf(v0.z); o[3] = (short)f2bf(v0.w);
    o[4] = (short)f2bf(v1.x); o[5] = (short)f2bf(v1.y);
    o[6] = (short)f2bf(v1.z); o[7] = (short)f2bf(v1.w);
    *(short8*)(bh16 + hh * 1048576 + base_ts) = o;
  }
}

// ---------------------------------------------------------------- replicate b=0 -> b=1,2,3 (fallback only)
__global__ __launch_bounds__(256) void bias_copy_kernel(float* __restrict__ out1)
{
  int idx = blockIdx.x * 256 + threadIdx.x;  // [0, 4M) units of float4
  float4 v = *(const float4*)&out1[idx * 4];
  *(float4*)&out1[16777216 + idx * 4] = v;
  *(float4*)&out1[33554432 + idx * 4] = v;
  *(float4*)&out1[50331648 + idx * 4] = v;
}

// ---------------------------------------------------------------- flash attention
// grid (64 bh, 16 qtiles); 4 INDEPENDENT waves/block (no barriers), 16 q-rows/wave.
// Pb stride 68 u16: conflict-free writes, 4-way (1.58x) reads vs 16-way before.
__global__ __launch_bounds__(256) void attn_kernel(
    const u16* __restrict__ qs, const u16* __restrict__ kko, const u16* __restrict__ vt,
    const float* __restrict__ gw, const float* __restrict__ gb, const float* __restrict__ ga,
    const u16* __restrict__ bh16, u16* __restrict__ ao)
{
  __shared__ __align__(16) u16 Pb[4][16 * 68];
  int wid = threadIdx.x >> 6, lane = threadIdx.x & 63;
  int l15 = lane & 15, quad = lane >> 4;
  int bh = blockIdx.x;
  int b = bh >> 4, h = bh & 15;
  int q0 = blockIdx.y * 64 + wid * 16;
  const u16* Q = qs + bh * 65536;
  const u16* K = kko + bh * 65536;
  const u16* V = vt + bh * 65536;        // [hd][t]
  const u16* Bi = bh16 + h * 1048576;    // bf16 [t][s]
  u16* pb = &Pb[wid][0];

  // ---- gate for row q0 + l15 (all lanes compute; quads duplicate) ----
  const u16* qrow = Q + (q0 + l15) * 64;
  float e[8];
#pragma unroll
  for (int i = 0; i < 8; i++) e[i] = gb[i];
  for (int j = 0; j < 64; j++) {
    float ql = bf2f(qrow[j]) * 256.0f;   // qs holds q*0.125; ql = raw_q*32
#pragma unroll
    for (int i = 0; i < 8; i++) e[i] += ql * gw[i * 64 + j];
  }
  float u0 = e[0] + e[1] + e[2] + e[3];
  float u1 = e[4] + e[5] + e[6] + e[7];
  float sa = 1.0f / (1.0f + __expf(-u0));
  float sb = 1.0f / (1.0f + __expf(-u1));
  float gv = sa * (sb * ga[h] - 1.0f) + 2.0f;

  short8 qf0 = *(const short8*)&Q[(q0 + l15) * 64 + quad * 8];
  short8 qf1 = *(const short8*)&Q[(q0 + l15) * 64 + quad * 8 + 32];
  float gt[4], mrun[4], lsum[4];
#pragma unroll
  for (int r = 0; r < 4; r++) {
    gt[r] = __shfl(gv, quad * 4 + r, 64);
    mrun[r] = -1e30f;
    lsum[r] = 0.f;       // LANE-PARTIAL denominator; reduced once at the end
  }
  floatx4 zero4 = {0.f, 0.f, 0.f, 0.f};
  floatx4 accO[4];
#pragma unroll
  for (int ni = 0; ni < 4; ni++) accO[ni] = zero4;

  for (int s0 = 0; s0 < 1024; s0 += 64) {
    // hoist bias loads: overlap L2 latency with QK MFMAs
    float bi[4][4];
#pragma unroll
    for (int r = 0; r < 4; r++) {
      int t = q0 + quad * 4 + r;
#pragma unroll
      for (int j = 0; j < 4; j++)
        bi[r][j] = bf2f(Bi[t * 1024 + s0 + j * 16 + l15]);
    }
    floatx4 sc[4];
#pragma unroll
    for (int j = 0; j < 4; j++) sc[j] = zero4;
#pragma unroll
    for (int j = 0; j < 4; j++) {
      short8 kf = *(const short8*)&K[(s0 + j * 16 + l15) * 64 + quad * 8];
      sc[j] = MFMA16(qf0, kf, sc[j]);
      kf = *(const short8*)&K[(s0 + j * 16 + l15) * 64 + quad * 8 + 32];
      sc[j] = MFMA16(qf1, kf, sc[j]);
    }

#pragma unroll
    for (int r = 0; r < 4; r++) {
      float v[4];
#pragma unroll
      for (int j = 0; j < 4; j++) v[j] = sc[j][r] + gt[r] * bi[r][j];
      float mt = fmaxf(fmaxf(v[0], v[1]), fmaxf(v[2], v[3]));
#pragma unroll
      for (int m = 1; m < 16; m <<= 1) mt = fmaxf(mt, __shfl_xor(mt, m, 64));
      float mnew = fmaxf(mrun[r], mt);
      float alpha = __expf(fmaxf(mrun[r] - mnew, -80.0f));  // first-iter safe
      float p[4];
#pragma unroll
      for (int j = 0; j < 4; j++) p[j] = __expf(v[j] - mnew);
      lsum[r] = lsum[r] * alpha + (p[0] + p[1]) + (p[2] + p[3]);
      mrun[r] = mnew;
#pragma unroll
      for (int ni = 0; ni < 4; ni++) accO[ni][r] *= alpha;
#pragma unroll
      for (int j = 0; j < 4; j++)
        pb[(quad * 4 + r) * 68 + j * 16 + l15] = f2bf(p[j]);
    }
    // wave-private LDS RAW: drain this wave's DS writes before cross-lane read.
    // (LDS pipeline is in-order per wave; no inter-wave sharing of Pb[wid].)
    __asm__ __volatile__("s_waitcnt lgkmcnt(0)" ::: "memory");
    short4v a0 = *(const short4v*)&pb[l15 * 68 + quad * 8];
    short4v a1 = *(const short4v*)&pb[l15 * 68 + quad * 8 + 4];
    short4v a2 = *(const short4v*)&pb[l15 * 68 + 32 + quad * 8];
    short4v a3 = *(const short4v*)&pb[l15 * 68 + 32 + quad * 8 + 4];
    short8 pf0, pf1;
#pragma unroll
    for (int i = 0; i < 4; i++) { pf0[i] = a0[i]; pf0[4 + i] = a1[i]; pf1[i] = a2[i]; pf1[4 + i] = a3[i]; }
#pragma unroll
    for (int ni = 0; ni < 4; ni++) {
      short8 vf = *(const short8*)&V[(ni * 16 + l15) * 1024 + s0 + quad * 8];
      accO[ni] = MFMA16(pf0, vf, accO[ni]);
      vf = *(const short8*)&V[(ni * 16 + l15) * 1024 + s0 + 32 + quad * 8];
      accO[ni] = MFMA16(pf1, vf, accO[ni]);
    }
  }
  // final denominator reduction (once, instead of per-iteration)
  float linv[4];
#pragma unroll
  for (int r = 0; r < 4; r++) {
    float ls = lsum[r];
#pragma unroll
    for (int m = 1; m < 16; m <<= 1) ls += __shfl_xor(ls, m, 64);
    linv[r] = 1.0f / ls;
  }
#pragma unroll
  for (int ni = 0; ni < 4; ni++) {
#pragma unroll
    for (int r = 0; r < 4; r++) {
      int t = q0 + quad * 4 + r;
      ao[(b * 1024 + t) * 1024 + h * 64 + ni * 16 + l15] = f2bf(accO[ni][r] * linv[r]);
    }
  }
}

// ---------------------------------------------------------------- output projection + residual (fp32 out)
__global__ __launch_bounds__(256) void oproj_kernel(
    const u16* __restrict__ ao, const u16* __restrict__ wob, const float* __restrict__ bo,
    const float* __restrict__ x, float* __restrict__ out)
{
  __shared__ u16 As[128 * 32];
  __shared__ u16 Bs[128 * 32];
  int tid = threadIdx.x;
  int wid = tid >> 6, lane = tid & 63;
  int wm = wid >> 1, wn = wid & 1;
  int l15 = lane & 15, quad = lane >> 4;
  int m0 = blockIdx.y * 128;
  int n0 = blockIdx.x * 128;

  floatx4 zero4 = {0.f, 0.f, 0.f, 0.f};
  floatx4 acc[4][4];
#pragma unroll
  for (int i = 0; i < 4; i++)
#pragma unroll
    for (int j = 0; j < 4; j++) acc[i][j] = zero4;

  int lr = tid >> 2;
  int lc = (tid & 3) * 8;
  u16* asw = As + wid * 512;
  u16* bsw = Bs + wid * 512;

  for (int kt = 0; kt < 1024; kt += 32) {
    gl_lds16(&ao[(m0 + lr) * 1024 + kt + lc],       asw);
    gl_lds16(&ao[(m0 + lr + 64) * 1024 + kt + lc],  asw + 2048);
    gl_lds16(&wob[(n0 + lr) * 1024 + kt + lc],      bsw);
    gl_lds16(&wob[(n0 + lr + 64) * 1024 + kt + lc], bsw + 2048);
    __syncthreads();
    short8 af[4], bf[4];
#pragma unroll
    for (int mi = 0; mi < 4; mi++)
      af[mi] = *(const short8*)&As[(wm * 64 + mi * 16 + l15) * 32 + quad * 8];
#pragma unroll
    for (int ni = 0; ni < 4; ni++)
      bf[ni] = *(const short8*)&Bs[(wn * 64 + ni * 16 + l15) * 32 + quad * 8];
#pragma unroll
    for (int mi = 0; mi < 4; mi++)
#pragma unroll
      for (int ni = 0; ni < 4; ni++)
        acc[mi][ni] = MFMA16(af[mi], bf[ni], acc[mi][ni]);
    __syncthreads();
  }

#pragma unroll
  for (int mi = 0; mi < 4; mi++) {
#pragma unroll
    for (int ni = 0; ni < 4; ni++) {
#pragma unroll
      for (int r = 0; r < 4; r++) {
        int row = m0 + wm * 64 + mi * 16 + quad * 4 + r;
        int c = n0 + wn * 64 + ni * 16 + l15;
        out[row * 1024 + c] = acc[mi][ni][r] + bo[c] + x[row * 1024 + c];
      }
    }
  }
}

// ---------------------------------------------------------------- launch
extern "C" void kernel_launch(void* const* d_in, const int* in_sizes, int n_in,
                              void* d_out, int out_size, void* d_ws, size_t ws_size,
                              hipStream_t stream) {
  const float* x    = (const float*)d_in[0];
  const float* ln_w = (const float*)d_in[1];
  const float* ln_b = (const float*)d_in[2];
  const float* wq   = (const float*)d_in[3];
  const float* bq   = (const float*)d_in[4];
  const float* wk   = (const float*)d_in[5];
  const float* bk   = (const float*)d_in[6];
  const float* wv   = (const float*)d_in[7];
  const float* bv   = (const float*)d_in[8];
  const float* wo   = (const float*)d_in[9];
  const float* bo   = (const float*)d_in[10];
  const float* rel  = (const float*)d_in[11];
  const float* gw   = (const float*)d_in[12];
  const float* gb   = (const float*)d_in[13];
  const float* ga   = (const float*)d_in[14];

  float* out0  = (float*)d_out;
  float* out1f = out0 + 4194304;   // pos_bias_out, 64M floats (256 MB)

  // scratch: 80 MB total (6x8MB bf16 bufs + 32MB bf16 bias copy)
  int big_ws = (ws_size >= (size_t)(96u << 20)) ? 1 : 0;
  char* sb = big_ws ? (char*)d_ws : (char*)(out1f + 16777216);  // fallback: out1 b=1,2 regions
  u16* hbb = (u16*)(sb);                  // 8 MB  LN(x) bf16
  u16* wbb = (u16*)(sb + (8u << 20));     // 8 MB  wq|wk|wv|wo bf16
  u16* qsb = (u16*)(sb + (16u << 20));    // 8 MB  q*0.125 [b,h,t,hd]
  u16* kkb = (u16*)(sb + (24u << 20));    // 8 MB  [b,h,t,hd]
  u16* vtb = (u16*)(sb + (32u << 20));    // 8 MB  [b,h,hd,t]
  u16* aob = (u16*)(sb + (40u << 20));    // 8 MB  attn out
  u16* bhb = (u16*)(sb + (48u << 20));    // 32 MB bf16 bias [h][t][s]

  ln_kernel<<<1024, 256, 0, stream>>>(x, ln_w, ln_b, hbb);
  convw_kernel<<<2048, 256, 0, stream>>>(wq, wk, wv, wo, wbb);
  qkv_kernel<<<dim3(24, 32), 256, 0, stream>>>(hbb, wbb, bq, bk, bv, qsb, kkb, vtb);
  bias0_kernel<<<512, 256, 0, stream>>>(rel, out1f, bhb, big_ws);
  attn_kernel<<<dim3(64, 16), 256, 0, stream>>>(qsb, kkb, vtb, gw, gb, ga, bhb, aob);
  oproj_kernel<<<dim3(8, 32), 256, 0, stream>>>(aob, wbb + 3145728, bo, x, out0);
  if (!big_ws)
    bias_copy_kernel<<<16384, 256, 0, stream>>>(out1f);  // replicate b=0 -> b=1,2,3
}